// Round 8
// baseline (199.696 us; speedup 1.0000x reference)
//
#include <hip/hip_runtime.h>
#include <hip/hip_bf16.h>
#include <math.h>

// Delta-rule linear attention, chunked + MFMA bf16, bf16 state buffer.
// B=8, S=4096, D=256, L=128 -> C=32 chunks/batch, 256 chunks total.
// R8: K3 rebuilt for TRUE 2 blocks/CU without spill:
//   - R7 counters: K3 = 40.4us, MfmaUtil 7.2%, VALU 8%, hbm 33%, occ 15.8%
//     -> latency-bound serial phase chain, needs TLP.
//   - LDS union 70KB (R4-verified overlay): QB[128][258] (entry..QH), then
//     Tm[128][138]+VT[256][66] overlay; T carried in tpk[8] regs through QH.
//   - odd-dword strides (258/138/66) kill the stride-264 4-bank-step
//     conflicts (1.77M measured).
//   - VGPR <= 128 by single-fragment inner loops (bfq/bfv transients 4-8
//     regs, not 32); launch_bounds(512,2) = 128-VGPR tier (NOT R4's
//     (512,4)=64 clamp that spilled).
// K1 = R6 (2 blk/CU, no BN, direct stores). K2 unchanged.
// ws: A/H buffer [256][256][256] bf16 in TRANSPOSED [j][i] layout (33.5 MB),
//     then P [256] f32.

#define B_ 8
#define S_ 4096
#define D_ 256
#define L_ 128
#define C_ (S_ / L_)      // 32
#define BC_ (B_ * C_)     // 256
#define STK 66            // u16 stride for transposed [.][s64] tiles
#define QBS 258           // QB u16 stride (129 dwords, odd -> conflict-free)
#define TMS 138           // Tm u16 stride (69 dwords, odd)

typedef __attribute__((ext_vector_type(8))) short s8v;   // 8 bf16 (4 VGPR)
typedef __attribute__((ext_vector_type(4))) float f4v;   // MFMA acc
typedef unsigned short u16;
typedef unsigned int u32;

__device__ __forceinline__ u32 pk2(float lo, float hi) {  // v_cvt_pk_bf16_f32
  union { __hip_bfloat162 h; u32 u; } cv;
  cv.h = __float22bfloat162_rn(make_float2(lo, hi));
  return cv.u;
}
__device__ __forceinline__ s8v pack8(const float4 a, const float4 b) {
  union { u32 u[4]; s8v v; } r;
  r.u[0] = pk2(a.x, a.y); r.u[1] = pk2(a.z, a.w);
  r.u[2] = pk2(b.x, b.y); r.u[3] = pk2(b.z, b.w);
  return r.v;
}

// ---------------------------------------------------------------------------
// Kernel 1: A[bc][j][i] = sum_{s<128} w_s k_s[i] v_s[j]  (bf16, [j][i])
//           P[bc] = prod_s beta_s.   2 blocks/CU, no spill (R6).
// ---------------------------------------------------------------------------
__global__ __launch_bounds__(512, 2) void ks_summary13(
    const float* __restrict__ kg, const float* __restrict__ vg,
    const float* __restrict__ beta, u16* __restrict__ A,
    float* __restrict__ P)
{
  __shared__ float ls[L_];
  __shared__ __align__(16) u16 U[2][256 * STK];   // K^T halves, then V^T

  const int bc = blockIdx.x;
  const int b = bc / C_, c = bc % C_;
  const int tid = threadIdx.x;
  const float* betap = beta + (size_t)b * S_ + (size_t)c * L_;
  const float* kbase = kg + ((size_t)b * S_ + (size_t)c * L_) * D_;
  const float* vbase = vg + ((size_t)b * S_ + (size_t)c * L_) * D_;

  const int hh = tid >> 8;            // s-half this thread stages
  const int t2 = tid & 255;
  const int iLs = t2 & 7;
  const int s0s = (t2 >> 3) * 2;      // local s-pair base 0..62
  const int sg = hh * 64 + s0s;       // global s

  // beta first (feeds the scan chain), then the K stream only (64 VGPR)
  float bx0 = 1.f, bx1 = 1.f;
  if (tid < 64) { bx0 = betap[tid]; bx1 = betap[64 + tid]; }

  float4 kp[16];
  {
    const float* k0 = kbase + (size_t)sg * D_;
#pragma unroll
    for (int p = 0; p < 8; ++p) {
      const int i0 = p * 32 + iLs * 4;
      kp[2 * p]     = *(const float4*)(k0 + i0);
      kp[2 * p + 1] = *(const float4*)(k0 + D_ + i0);
    }
  }

  // 128-step prefix log2(beta) scan by wave 0 (overlaps the K load latency)
  if (tid < 64) {
    float x = log2f(fmaxf(bx0, 1e-30f));
#pragma unroll
    for (int off = 1; off < 64; off <<= 1) {
      float y = __shfl_up(x, off);
      if (tid >= off) x += y;
    }
    ls[tid] = x;
    const float tot0 = __shfl(x, 63);
    float z = log2f(fmaxf(bx1, 1e-30f));
#pragma unroll
    for (int off = 1; off < 64; off <<= 1) {
      float y = __shfl_up(z, off);
      if (tid >= off) z += y;
    }
    ls[64 + tid] = z + tot0;
  }
  __syncthreads();
  const float ltot = ls[L_ - 1];
  if (tid == 0) P[bc] = exp2f(ltot);

  // ---- pack w-scaled K^T from registers -> LDS (kp dies here) ----
  {
    const float w0 = exp2f(ltot - ls[sg]);
    const float w1 = exp2f(ltot - ls[sg + 1]);
    u16* dst = U[hh];
#pragma unroll
    for (int p = 0; p < 8; ++p) {
      const int i0 = p * 32 + iLs * 4;
      const float4 a0 = kp[2 * p], a1 = kp[2 * p + 1];
      *(u32*)&dst[(i0 + 0) * STK + s0s] = pk2(a0.x * w0, a1.x * w1);
      *(u32*)&dst[(i0 + 1) * STK + s0s] = pk2(a0.y * w0, a1.y * w1);
      *(u32*)&dst[(i0 + 2) * STK + s0s] = pk2(a0.z * w0, a1.z * w1);
      *(u32*)&dst[(i0 + 3) * STK + s0s] = pk2(a0.w * w0, a1.w * w1);
    }
  }
  __syncthreads();

  const int lane = tid & 63, wave = tid >> 6;
  const int quad = lane >> 4, l15 = lane & 15;
  const int i0w = wave * 32;          // i-strip for this wave

  // issue V pass-0 loads (32 VGPR) BEFORE the af ds_reads
  float4 vb[8];
  {
    const float* v0 = vbase + (size_t)sg * D_;
#pragma unroll
    for (int p = 0; p < 4; ++p) {
      const int i0 = p * 32 + iLs * 4;
      vb[2 * p]     = *(const float4*)(v0 + i0);
      vb[2 * p + 1] = *(const float4*)(v0 + D_ + i0);
    }
  }

  // cache A-operand (K^T) fragments covering all 4 k-steps (s=128)
  s8v af[2][4];
#pragma unroll
  for (int mt = 0; mt < 2; ++mt)
#pragma unroll
    for (int ks = 0; ks < 4; ++ks)
      af[mt][ks] = *(const s8v*)&U[ks >> 1][(i0w + mt * 16 + l15) * STK +
                                            (ks & 1) * 32 + quad * 8];
  __syncthreads();   // all af reads done; U may be overwritten

  // ---- pack V^T over K^T, two half-passes (peak stage regs = 32) ----
  {
    u16* dst = U[hh];
#pragma unroll
    for (int p = 0; p < 4; ++p) {
      const int i0 = p * 32 + iLs * 4;
      const float4 a0 = vb[2 * p], a1 = vb[2 * p + 1];
      *(u32*)&dst[(i0 + 0) * STK + s0s] = pk2(a0.x, a1.x);
      *(u32*)&dst[(i0 + 1) * STK + s0s] = pk2(a0.y, a1.y);
      *(u32*)&dst[(i0 + 2) * STK + s0s] = pk2(a0.z, a1.z);
      *(u32*)&dst[(i0 + 3) * STK + s0s] = pk2(a0.w, a1.w);
    }
    const float* v0 = vbase + (size_t)sg * D_;
#pragma unroll
    for (int p = 4; p < 8; ++p) {
      const int i0 = p * 32 + iLs * 4;
      const float4 a0 = *(const float4*)(v0 + i0);
      const float4 a1 = *(const float4*)(v0 + D_ + i0);
      *(u32*)&dst[(i0 + 0) * STK + s0s] = pk2(a0.x, a1.x);
      *(u32*)&dst[(i0 + 1) * STK + s0s] = pk2(a0.y, a1.y);
      *(u32*)&dst[(i0 + 2) * STK + s0s] = pk2(a0.z, a1.z);
      *(u32*)&dst[(i0 + 3) * STK + s0s] = pk2(a0.w, a1.w);
    }
  }
  __syncthreads();

  u16* Ab = A + (size_t)bc * D_ * D_;

  // j-loop: barrier-free; C-fragments stored directly
  for (int ng = 0; ng < 4; ++ng) {    // j-groups of 64
    f4v acc[2][4];
#pragma unroll
    for (int mt = 0; mt < 2; ++mt)
#pragma unroll
      for (int nt = 0; nt < 4; ++nt) acc[mt][nt] = (f4v){0.f, 0.f, 0.f, 0.f};

#pragma unroll
    for (int ks = 0; ks < 4; ++ks) {
      const int so = (ks & 1) * 32 + quad * 8;
      s8v bv[4];
#pragma unroll
      for (int nt = 0; nt < 4; ++nt)
        bv[nt] = *(const s8v*)&U[ks >> 1][(ng * 64 + nt * 16 + l15) * STK + so];
#pragma unroll
      for (int mt = 0; mt < 2; ++mt)
#pragma unroll
        for (int nt = 0; nt < 4; ++nt)
          acc[mt][nt] = __builtin_amdgcn_mfma_f32_16x16x32_bf16(
              af[mt][ks], bv[nt], acc[mt][nt], 0, 0, 0);
    }
#pragma unroll
    for (int mt = 0; mt < 2; ++mt)
#pragma unroll
      for (int nt = 0; nt < 4; ++nt) {
        const int jl = ng * 64 + nt * 16 + l15;
        uint2 w;
        w.x = pk2(acc[mt][nt][0], acc[mt][nt][1]);
        w.y = pk2(acc[mt][nt][2], acc[mt][nt][3]);
        *(uint2*)&Ab[(size_t)jl * D_ + i0w + mt * 16 + quad * 4] = w;
      }
  }
}

// ---------------------------------------------------------------------------
// Kernel 2: register-batched chunk scan (unchanged).
// ---------------------------------------------------------------------------
__global__ __launch_bounds__(256) void ks_scan13(
    u16* __restrict__ A, const float* __restrict__ P)
{
  const int g = blockIdx.x;                       // 512 blocks
  const int b = g >> 6;                           // 64 blocks / batch
  const int unit = ((g & 63) << 8) + threadIdx.x; // uint2 unit 0..16383
  u16* base = A + (size_t)b * ((size_t)C_ * D_ * D_) + (size_t)unit * 4;
  const float* Pb = P + b * C_;

  uint2 d[C_];
#pragma unroll
  for (int c = 0; c < C_; ++c)
    d[c] = *(const uint2*)(base + (size_t)c * (D_ * D_));

  float h0 = 0.f, h1 = 0.f, h2 = 0.f, h3 = 0.f;
#pragma unroll
  for (int c = 0; c < C_; ++c) {
    const float pc = Pb[c];
    const uint2 u = d[c];
    const float a0 = __uint_as_float(u.x << 16);
    const float a1 = __uint_as_float(u.x & 0xFFFF0000u);
    const float a2 = __uint_as_float(u.y << 16);
    const float a3 = __uint_as_float(u.y & 0xFFFF0000u);
    d[c].x = pk2(h0, h1);
    d[c].y = pk2(h2, h3);
    h0 = fmaf(pc, h0, a0); h1 = fmaf(pc, h1, a1);
    h2 = fmaf(pc, h2, a2); h3 = fmaf(pc, h3, a3);
  }
#pragma unroll
  for (int c = 0; c < C_; ++c)
    *(uint2*)(base + (size_t)c * (D_ * D_)) = d[c];
}

// ---------------------------------------------------------------------------
// Kernel 3: O = Tm @ V + diag(c) Q @ H.   512 thr / 8 waves, 2 blocks/CU.
// LDS union raw[34560] u16 (69.1 KB):
//   QB [128][QBS=258] = 33024 u16     (alive: entry .. end of QH)
//   Tm [128][TMS=138] = 17664 u16 at raw+0      (post-QH overlay)
//   VT [256][STK=66]  = 16896 u16 at raw+17664  (post-QH overlay, half-buf)
// T carried in tpk[8] regs through QH (R4-verified-correct pattern).
// Single-fragment inner loops keep peak VGPR <= 128 (2-block tier).
// ---------------------------------------------------------------------------
__global__ __launch_bounds__(512, 2) void ks_output13(
    const float* __restrict__ qg, const float* __restrict__ kg,
    const float* __restrict__ vg, const float* __restrict__ beta,
    const u16* __restrict__ Hg, float* __restrict__ outg)
{
  __shared__ float ls[L_];
  __shared__ float cv[L_];
  __shared__ __align__(16) u16 raw[34560];       // 69.1 KB union

  const int bc = blockIdx.x;
  const int b = bc / C_, c = bc % C_;
  const int tid = threadIdx.x;
  const float* betap = beta + (size_t)b * S_ + (size_t)c * L_;
  const float* qbase = qg + ((size_t)b * S_ + (size_t)c * L_) * D_;
  const float* kbase = kg + ((size_t)b * S_ + (size_t)c * L_) * D_;
  const float* vbase = vg + ((size_t)b * S_ + (size_t)c * L_) * D_;
  const u16* Hb = Hg + (size_t)bc * D_ * D_;

  const int lane = tid & 63, wave = tid >> 6;
  const int quad = lane >> 4, l15 = lane & 15;
  const int j0w = wave * 32;
  const int mA = wave * 16;             // s-tile base for phase A

  // beta first (feeds scan), then Q prefetch (qp dies at QB stage)
  float bx0 = 1.f, bx1 = 1.f;
  if (tid < 64) { bx0 = betap[tid]; bx1 = betap[64 + tid]; }

  const int qt = tid >> 2, qc = (tid & 3) * 8;
  float4 qp[16];
  {
    const float* src = qbase + (size_t)qt * D_ + qc;
#pragma unroll
    for (int p = 0; p < 8; ++p) {
      qp[2 * p]     = *(const float4*)(src + p * 32);
      qp[2 * p + 1] = *(const float4*)(src + p * 32 + 4);
    }
  }

  // prefix log2(beta) scan; wave 0 also writes cv (visible at B1)
  if (tid < 64) {
    float x = log2f(fmaxf(bx0, 1e-30f));
#pragma unroll
    for (int off = 1; off < 64; off <<= 1) {
      float y = __shfl_up(x, off);
      if (tid >= off) x += y;
    }
    ls[tid] = x;
    cv[tid] = exp2f(x);
    const float tot0 = __shfl(x, 63);
    float z = log2f(fmaxf(bx1, 1e-30f));
#pragma unroll
    for (int off = 1; off < 64; off <<= 1) {
      float y = __shfl_up(z, off);
      if (tid >= off) z += y;
    }
    ls[64 + tid] = z + tot0;
    cv[64 + tid] = exp2f(z + tot0);
  }

  // ---- stage QB (stride 258, odd-dword -> conflict-free) ----
  u16* QB = raw;
#pragma unroll
  for (int p = 0; p < 8; ++p)
    *(s8v*)&QB[qt * QBS + qc + p * 32] = pack8(qp[2 * p], qp[2 * p + 1]);
  __syncthreads();   // B1: QB + ls + cv visible

  // ---- phase A: T = Q K^T; result kept in registers (tpk) ----
  uint2 tpk[8];
  {
    f4v accA[8];
#pragma unroll
    for (int i = 0; i < 8; ++i) accA[i] = (f4v){0.f, 0.f, 0.f, 0.f};
#pragma unroll
    for (int kd = 0; kd < 8; ++kd) {
      const int d0 = kd * 32 + quad * 8;
      const float* krow = kbase + (size_t)(mA + l15) * D_ + d0;
      const s8v afr = pack8(*(const float4*)krow, *(const float4*)(krow + 4));
#pragma unroll
      for (int nt = 0; nt < 8; ++nt) {
        const s8v bf = *(const s8v*)&QB[(nt * 16 + l15) * QBS + d0];
        accA[nt] = __builtin_amdgcn_mfma_f32_16x16x32_bf16(afr, bf, accA[nt],
                                                           0, 0, 0);
      }
    }
    // rows = s (quad*4+r), cols = t (l15): mask+decay, pack s-pairs
#pragma unroll
    for (int nt = 0; nt < 8; ++nt) {
      const int t = nt * 16 + l15;
      const float lt = ls[t];
      const int s0 = mA + quad * 4;
      float v4[4];
#pragma unroll
      for (int r = 0; r < 4; ++r) {
        const int s = s0 + r;
        v4[r] = (s <= t) ? accA[nt][r] * exp2f(lt - ls[s]) : 0.f;
      }
      tpk[nt].x = pk2(v4[0], v4[1]);
      tpk[nt].y = pk2(v4[2], v4[3]);
    }
  }

  // preload first H k-step (global)
  s8v hc[2];
#pragma unroll
  for (int mt = 0; mt < 2; ++mt)
    hc[mt] = *(const s8v*)(Hb + (size_t)(j0w + mt * 16 + l15) * D_ + quad * 8);

  // ---- Q @ H (QH reads only QB, visible since B1; no barrier needed) ----
  // single-bfq inner loop keeps transients at 4 regs (VGPR <= 128 tier)
  f4v acc[2][8];
#pragma unroll
  for (int mt = 0; mt < 2; ++mt)
#pragma unroll
    for (int nt = 0; nt < 8; ++nt) acc[mt][nt] = (f4v){0.f, 0.f, 0.f, 0.f};

#pragma unroll
  for (int ks = 0; ks < 8; ++ks) {
    const int io = ks * 32 + quad * 8;
    s8v hn[2] = {hc[0], hc[1]};
    if (ks < 7) {
#pragma unroll
      for (int mt = 0; mt < 2; ++mt)
        hn[mt] = *(const s8v*)(Hb + (size_t)(j0w + mt * 16 + l15) * D_ +
                               io + 32);
    }
#pragma unroll
    for (int nt = 0; nt < 8; ++nt) {
      const s8v bfq = *(const s8v*)&QB[(nt * 16 + l15) * QBS + io];
      acc[0][nt] = __builtin_amdgcn_mfma_f32_16x16x32_bf16(
          hc[0], bfq, acc[0][nt], 0, 0, 0);
      acc[1][nt] = __builtin_amdgcn_mfma_f32_16x16x32_bf16(
          hc[1], bfq, acc[1][nt], 0, 0, 0);
    }
    hc[0] = hn[0]; hc[1] = hn[1];
  }
  // scale by c_t
#pragma unroll
  for (int nt = 0; nt < 8; ++nt) {
    const float ct = cv[nt * 16 + l15];
#pragma unroll
    for (int mt = 0; mt < 2; ++mt) {
      acc[mt][nt][0] *= ct; acc[mt][nt][1] *= ct;
      acc[mt][nt][2] *= ct; acc[mt][nt][3] *= ct;
    }
  }

  __syncthreads();   // B2: all QB reads done; overlay region free

  u16* Tm = raw;                 // [128][TMS]
  u16* VT = raw + 17664;         // [256][STK], half-buffer
  const int iL3 = tid & 15;
  const int s03 = ((tid >> 4) & 31) * 2;

  // ---- stage Tm (from tpk) + VT half 0 (loads issued first) ----
  {
    const float* a0 = vbase + (size_t)s03 * D_;
    float4 f0[4], f1[4];
#pragma unroll
    for (int p = 0; p < 4; ++p) {
      const int i0 = p * 64 + iL3 * 4;
      f0[p] = *(const float4*)(a0 + i0);
      f1[p] = *(const float4*)(a0 + D_ + i0);
    }
    // Tm stores (independent of the V loads above -> overlap latency)
#pragma unroll
    for (int nt = 0; nt < 8; ++nt)
      *(uint2*)&Tm[(nt * 16 + l15) * TMS + mA + quad * 4] = tpk[nt];
#pragma unroll
    for (int p = 0; p < 4; ++p) {
      const int i0 = p * 64 + iL3 * 4;
      *(u32*)&VT[(i0 + 0) * STK + s03] = pk2(f0[p].x, f1[p].x);
      *(u32*)&VT[(i0 + 1) * STK + s03] = pk2(f0[p].y, f1[p].y);
      *(u32*)&VT[(i0 + 2) * STK + s03] = pk2(f0[p].z, f1[p].z);
      *(u32*)&VT[(i0 + 3) * STK + s03] = pk2(f0[p].w, f1[p].w);
    }
  }

  // issue V half-1 loads; they drain under Tm@V h0
  float4 vp1[8];
  {
    const float* b0 = vbase + (size_t)(64 + s03) * D_;
#pragma unroll
    for (int p = 0; p < 4; ++p) {
      const int i0 = p * 64 + iL3 * 4;
      vp1[2 * p]     = *(const float4*)(b0 + i0);
      vp1[2 * p + 1] = *(const float4*)(b0 + D_ + i0);
    }
  }
  __syncthreads();   // B3: VT h0 + Tm visible

  // ---- Tm @ V half 0 (single-bfv inner loop) ----
#pragma unroll
  for (int ks = 0; ks < 2; ++ks) {
    const int so = ks * 32 + quad * 8;
    s8v afv[2];
#pragma unroll
    for (int mt = 0; mt < 2; ++mt)
      afv[mt] = *(const s8v*)&VT[(j0w + mt * 16 + l15) * STK + so];
#pragma unroll
    for (int nt = 0; nt < 8; ++nt) {
      const s8v bfv = *(const s8v*)&Tm[(nt * 16 + l15) * TMS + so];
      acc[0][nt] = __builtin_amdgcn_mfma_f32_16x16x32_bf16(
          afv[0], bfv, acc[0][nt], 0, 0, 0);
      acc[1][nt] = __builtin_amdgcn_mfma_f32_16x16x32_bf16(
          afv[1], bfv, acc[1][nt], 0, 0, 0);
    }
  }

  // ---- Tm @ V half 1: restage VT from vp1 ----
  __syncthreads();   // B4: all h0 reads done
  {
#pragma unroll
    for (int p = 0; p < 4; ++p) {
      const int i0 = p * 64 + iL3 * 4;
      const float4 a0 = vp1[2 * p], a1 = vp1[2 * p + 1];
      *(u32*)&VT[(i0 + 0) * STK + s03] = pk2(a0.x, a1.x);
      *(u32*)&VT[(i0 + 1) * STK + s03] = pk2(a0.y, a1.y);
      *(u32*)&VT[(i0 + 2) * STK + s03] = pk2(a0.z, a1.z);
      *(u32*)&VT[(i0 + 3) * STK + s03] = pk2(a0.w, a1.w);
    }
  }
  __syncthreads();   // B5
#pragma unroll
  for (int ks = 0; ks < 2; ++ks) {
    const int so = ks * 32 + quad * 8;
    s8v afv[2];
#pragma unroll
    for (int mt = 0; mt < 2; ++mt)
      afv[mt] = *(const s8v*)&VT[(j0w + mt * 16 + l15) * STK + so];
#pragma unroll
    for (int nt = 0; nt < 8; ++nt) {
      const s8v bfv = *(const s8v*)&Tm[(nt * 16 + l15) * TMS + 64 + so];
      acc[0][nt] = __builtin_amdgcn_mfma_f32_16x16x32_bf16(
          afv[0], bfv, acc[0][nt], 0, 0, 0);
      acc[1][nt] = __builtin_amdgcn_mfma_f32_16x16x32_bf16(
          afv[1], bfv, acc[1][nt], 0, 0, 0);
    }
  }

  // epilogue: float4 stores (r runs along j)
  float* ob = outg + ((size_t)b * S_ + (size_t)c * L_) * D_;
#pragma unroll
  for (int mt = 0; mt < 2; ++mt)
#pragma unroll
    for (int nt = 0; nt < 8; ++nt) {
      const int t = nt * 16 + l15;
      const int j0 = j0w + mt * 16 + quad * 4;
      float4 o;
      o.x = acc[mt][nt][0]; o.y = acc[mt][nt][1];
      o.z = acc[mt][nt][2]; o.w = acc[mt][nt][3];
      *(float4*)(ob + (size_t)t * D_ + j0) = o;
    }
}

// ---------------------------------------------------------------------------
extern "C" void kernel_launch(void* const* d_in, const int* in_sizes, int n_in,
                              void* d_out, int out_size, void* d_ws,
                              size_t ws_size, hipStream_t stream) {
  const float* q = (const float*)d_in[0];
  const float* k = (const float*)d_in[1];
  const float* v = (const float*)d_in[2];
  const float* beta = (const float*)d_in[3];
  float* out = (float*)d_out;

  u16* A = (u16*)d_ws;                                   // 33.5 MB bf16 state
  float* P = (float*)((char*)d_ws + (size_t)BC_ * D_ * D_ * sizeof(u16));

  ks_summary13<<<dim3(BC_), dim3(512), 0, stream>>>(k, v, beta, A, P);
  ks_scan13<<<dim3(512), dim3(256), 0, stream>>>(A, P);
  ks_output13<<<dim3(BC_), dim3(512), 0, stream>>>(q, k, v, beta, A, out);
}

// Round 9
// 170.624 us; speedup vs baseline: 1.1704x; 1.1704x over previous
//
#include <hip/hip_runtime.h>
#include <hip/hip_bf16.h>
#include <math.h>

// Delta-rule linear attention, chunked + MFMA bf16, bf16 state buffer.
// B=8, S=4096, D=256, L=128 -> C=32 chunks/batch, 256 chunks total.
// 3-kernel structure. Best verified config (R2/R5: 171.6-172.0 us).
// R9: exact revert of R8. Session evidence (R1-R8): K3 needs ~180 live
// VGPRs (1 blk/CU forced; 128-VGPR 2-blk tier strangles scheduling, +22us;
// 64-VGPR tier spills 120 MB, +40us); odd u16 strides break 16B LDS vector
// alignment; K1 2-blk/CU neutral; cooperative fusion +88us. This config is
// the measured optimum across all variants.
// ws: A/H buffer [256][256][256] bf16 in TRANSPOSED [j][i] layout (33.5 MB),
//     then P [256] f32.

#define B_ 8
#define S_ 4096
#define D_ 256
#define L_ 128
#define C_ (S_ / L_)      // 32
#define BC_ (B_ * C_)     // 256
#define STK 66            // u16 stride for transposed [.][s64] tiles

typedef __attribute__((ext_vector_type(8))) short s8v;   // 8 bf16 (4 VGPR)
typedef __attribute__((ext_vector_type(4))) float f4v;   // MFMA acc
typedef unsigned short u16;
typedef unsigned int u32;

__device__ __forceinline__ u32 pk2(float lo, float hi) {  // v_cvt_pk_bf16_f32
  union { __hip_bfloat162 h; u32 u; } cv;
  cv.h = __float22bfloat162_rn(make_float2(lo, hi));
  return cv.u;
}
__device__ __forceinline__ s8v pack8(const float4 a, const float4 b) {
  union { u32 u[4]; s8v v; } r;
  r.u[0] = pk2(a.x, a.y); r.u[1] = pk2(a.z, a.w);
  r.u[2] = pk2(b.x, b.y); r.u[3] = pk2(b.z, b.w);
  return r.v;
}

// ---------------------------------------------------------------------------
// Kernel 1: A[bc][j][i] = sum_{s<128} w_s k_s[i] v_s[j]  (bf16, [j][i])
//           P[bc] = prod_s beta_s.
// K+V prefetched to registers as ONE merged HBM stream before any barrier;
// BN double-buffered -> 1 barrier per j-group.
// ---------------------------------------------------------------------------
__global__ __launch_bounds__(512, 2) void ks_summary14(
    const float* __restrict__ kg, const float* __restrict__ vg,
    const float* __restrict__ beta, u16* __restrict__ A,
    float* __restrict__ P)
{
  __shared__ float ls[L_];
  __shared__ __align__(16) u16 U[2][256 * STK];   // K^T halves, then V^T
  __shared__ __align__(16) u16 BN[2][64 * 264];   // bounce, double-buffered

  const int bc = blockIdx.x;
  const int b = bc / C_, c = bc % C_;
  const int tid = threadIdx.x;
  const float* betap = beta + (size_t)b * S_ + (size_t)c * L_;
  const float* kbase = kg + ((size_t)b * S_ + (size_t)c * L_) * D_;
  const float* vbase = vg + ((size_t)b * S_ + (size_t)c * L_) * D_;

  const int hh = tid >> 8;            // s-half this thread stages
  const int t2 = tid & 255;
  const int iLs = t2 & 7;
  const int s0s = (t2 >> 3) * 2;      // local s-pair base 0..62
  const int sg = hh * 64 + s0s;       // global s

  // beta first (feeds the scan chain), then the bulk K+V streams
  float bx0 = 1.f, bx1 = 1.f;
  if (tid < 64) { bx0 = betap[tid]; bx1 = betap[64 + tid]; }

  float4 kp[16], vp[16];
  {
    const float* k0 = kbase + (size_t)sg * D_;
    const float* v0 = vbase + (size_t)sg * D_;
#pragma unroll
    for (int p = 0; p < 8; ++p) {
      const int i0 = p * 32 + iLs * 4;
      kp[2 * p]     = *(const float4*)(k0 + i0);
      kp[2 * p + 1] = *(const float4*)(k0 + D_ + i0);
    }
#pragma unroll
    for (int p = 0; p < 8; ++p) {
      const int i0 = p * 32 + iLs * 4;
      vp[2 * p]     = *(const float4*)(v0 + i0);
      vp[2 * p + 1] = *(const float4*)(v0 + D_ + i0);
    }
  }

  // 128-step prefix log2(beta) scan by wave 0 (overlaps the load latency)
  if (tid < 64) {
    float x = log2f(fmaxf(bx0, 1e-30f));
#pragma unroll
    for (int off = 1; off < 64; off <<= 1) {
      float y = __shfl_up(x, off);
      if (tid >= off) x += y;
    }
    ls[tid] = x;
    const float tot0 = __shfl(x, 63);
    float z = log2f(fmaxf(bx1, 1e-30f));
#pragma unroll
    for (int off = 1; off < 64; off <<= 1) {
      float y = __shfl_up(z, off);
      if (tid >= off) z += y;
    }
    ls[64 + tid] = z + tot0;
  }
  __syncthreads();
  const float ltot = ls[L_ - 1];
  if (tid == 0) P[bc] = exp2f(ltot);

  // ---- pack w-scaled K^T from registers -> LDS ----
  {
    const float w0 = exp2f(ltot - ls[sg]);
    const float w1 = exp2f(ltot - ls[sg + 1]);
    u16* dst = U[hh];
#pragma unroll
    for (int p = 0; p < 8; ++p) {
      const int i0 = p * 32 + iLs * 4;
      const float4 a0 = kp[2 * p], a1 = kp[2 * p + 1];
      *(u32*)&dst[(i0 + 0) * STK + s0s] = pk2(a0.x * w0, a1.x * w1);
      *(u32*)&dst[(i0 + 1) * STK + s0s] = pk2(a0.y * w0, a1.y * w1);
      *(u32*)&dst[(i0 + 2) * STK + s0s] = pk2(a0.z * w0, a1.z * w1);
      *(u32*)&dst[(i0 + 3) * STK + s0s] = pk2(a0.w * w0, a1.w * w1);
    }
  }
  __syncthreads();

  const int lane = tid & 63, wave = tid >> 6;
  const int quad = lane >> 4, l15 = lane & 15;
  const int i0w = wave * 32;          // i-strip for this wave

  // cache A-operand (K^T) fragments covering all 4 k-steps (s=128)
  s8v af[2][4];
#pragma unroll
  for (int mt = 0; mt < 2; ++mt)
#pragma unroll
    for (int ks = 0; ks < 4; ++ks)
      af[mt][ks] = *(const s8v*)&U[ks >> 1][(i0w + mt * 16 + l15) * STK +
                                            (ks & 1) * 32 + quad * 8];
  __syncthreads();

  // ---- pack V^T over K^T (data already in registers; no global wait) ----
  {
    u16* dst = U[hh];
#pragma unroll
    for (int p = 0; p < 8; ++p) {
      const int i0 = p * 32 + iLs * 4;
      const float4 a0 = vp[2 * p], a1 = vp[2 * p + 1];
      *(u32*)&dst[(i0 + 0) * STK + s0s] = pk2(a0.x, a1.x);
      *(u32*)&dst[(i0 + 1) * STK + s0s] = pk2(a0.y, a1.y);
      *(u32*)&dst[(i0 + 2) * STK + s0s] = pk2(a0.z, a1.z);
      *(u32*)&dst[(i0 + 3) * STK + s0s] = pk2(a0.w, a1.w);
    }
  }
  __syncthreads();

  u16* Ab = A + (size_t)bc * D_ * D_;

  for (int ng = 0; ng < 4; ++ng) {    // j-groups of 64
    f4v acc[2][4];
#pragma unroll
    for (int mt = 0; mt < 2; ++mt)
#pragma unroll
      for (int nt = 0; nt < 4; ++nt) acc[mt][nt] = (f4v){0.f, 0.f, 0.f, 0.f};

#pragma unroll
    for (int ks = 0; ks < 4; ++ks) {
      const int so = (ks & 1) * 32 + quad * 8;
      s8v bv[4];
#pragma unroll
      for (int nt = 0; nt < 4; ++nt)
        bv[nt] = *(const s8v*)&U[ks >> 1][(ng * 64 + nt * 16 + l15) * STK + so];
#pragma unroll
      for (int mt = 0; mt < 2; ++mt)
#pragma unroll
        for (int nt = 0; nt < 4; ++nt)
          acc[mt][nt] = __builtin_amdgcn_mfma_f32_16x16x32_bf16(
              af[mt][ks], bv[nt], acc[mt][nt], 0, 0, 0);
    }
    // C-frags -> bounce buffer (ng&1): ONE barrier per group; buffer ng&1 is
    // next rewritten at ng+2, after the ng+1 barrier -> race-free
    u16* BNb = BN[ng & 1];
#pragma unroll
    for (int mt = 0; mt < 2; ++mt)
#pragma unroll
      for (int nt = 0; nt < 4; ++nt) {
        const int jl = nt * 16 + l15;
        uint2 w;
        w.x = pk2(acc[mt][nt][0], acc[mt][nt][1]);
        w.y = pk2(acc[mt][nt][2], acc[mt][nt][3]);
        *(uint2*)&BNb[jl * 264 + i0w + mt * 16 + quad * 4] = w;
      }
    __syncthreads();
    // coalesced copy-out: 64 rows x 512 B (stores drain off-critical-path)
    {
      const int jl = tid >> 3;
      const int il = (tid & 7) * 8;
#pragma unroll
      for (int p = 0; p < 4; ++p) {
        const int iu = il + p * 64;
        *(s8v*)&Ab[(size_t)(ng * 64 + jl) * D_ + iu] =
            *(const s8v*)&BNb[jl * 264 + iu];
      }
    }
  }
}

// ---------------------------------------------------------------------------
// Kernel 2: register-batched chunk scan. Each thread owns a uint2 (4 elems);
// loads ALL 32 chunk values (independent, fully pipelined), runs the
// recurrence in registers, stores all 32. On exit A[bc] = state ENTERING c.
// ---------------------------------------------------------------------------
__global__ __launch_bounds__(256) void ks_scan14(
    u16* __restrict__ A, const float* __restrict__ P)
{
  const int g = blockIdx.x;                       // 512 blocks
  const int b = g >> 6;                           // 64 blocks / batch
  const int unit = ((g & 63) << 8) + threadIdx.x; // uint2 unit 0..16383
  u16* base = A + (size_t)b * ((size_t)C_ * D_ * D_) + (size_t)unit * 4;
  const float* Pb = P + b * C_;

  uint2 d[C_];
#pragma unroll
  for (int c = 0; c < C_; ++c)
    d[c] = *(const uint2*)(base + (size_t)c * (D_ * D_));

  float h0 = 0.f, h1 = 0.f, h2 = 0.f, h3 = 0.f;
#pragma unroll
  for (int c = 0; c < C_; ++c) {
    const float pc = Pb[c];
    const uint2 u = d[c];
    const float a0 = __uint_as_float(u.x << 16);
    const float a1 = __uint_as_float(u.x & 0xFFFF0000u);
    const float a2 = __uint_as_float(u.y << 16);
    const float a3 = __uint_as_float(u.y & 0xFFFF0000u);
    d[c].x = pk2(h0, h1);
    d[c].y = pk2(h2, h3);
    h0 = fmaf(pc, h0, a0); h1 = fmaf(pc, h1, a1);
    h2 = fmaf(pc, h2, a2); h3 = fmaf(pc, h3, a3);
  }
#pragma unroll
  for (int c = 0; c < C_; ++c)
    *(uint2*)(base + (size_t)c * (D_ * D_)) = d[c];
}

// ---------------------------------------------------------------------------
// Kernel 3: O = Tm @ V + diag(c) Q @ H.   512 thr / 8 waves, L=128.
// 1 block/CU (needs ~180 live VGPRs; 104 allocated at (512,2); 137 KB LDS).
// ---------------------------------------------------------------------------
__global__ __launch_bounds__(512, 2) void ks_output14(
    const float* __restrict__ qg, const float* __restrict__ kg,
    const float* __restrict__ vg, const float* __restrict__ beta,
    const u16* __restrict__ Hg, float* __restrict__ outg)
{
  __shared__ float ls[L_];
  __shared__ float cv[L_];
  __shared__ __align__(16) u16 QB[L_ * 264];     // [t][d] bf16   (67.6 KB)
  __shared__ __align__(16) u16 Tm[L_ * 136];     // [t][s] bf16   (34.8 KB)
  __shared__ __align__(16) u16 VT[256 * STK];    // [j][s-half]   (33.8 KB)

  const int bc = blockIdx.x;
  const int b = bc / C_, c = bc % C_;
  const int tid = threadIdx.x;
  const float* betap = beta + (size_t)b * S_ + (size_t)c * L_;
  const float* qbase = qg + ((size_t)b * S_ + (size_t)c * L_) * D_;
  const float* kbase = kg + ((size_t)b * S_ + (size_t)c * L_) * D_;
  const float* vbase = vg + ((size_t)b * S_ + (size_t)c * L_) * D_;
  const u16* Hb = Hg + (size_t)bc * D_ * D_;

  // beta first (feeds scan), then Q + V(h0) as one merged prefetch stream
  float bx0 = 1.f, bx1 = 1.f;
  if (tid < 64) { bx0 = betap[tid]; bx1 = betap[64 + tid]; }

  const int qt = tid >> 2, qc = (tid & 3) * 8;
  float4 qp[16];
  {
    const float* src = qbase + (size_t)qt * D_ + qc;
#pragma unroll
    for (int p = 0; p < 8; ++p) {
      qp[2 * p]     = *(const float4*)(src + p * 32);
      qp[2 * p + 1] = *(const float4*)(src + p * 32 + 4);
    }
  }
  const int iL3 = tid & 15;
  const int s03 = ((tid >> 4) & 31) * 2;
  float4 vp0[8];
  {
    const float* a0 = vbase + (size_t)s03 * D_;
#pragma unroll
    for (int p = 0; p < 4; ++p) {
      const int i0 = p * 64 + iL3 * 4;
      vp0[2 * p]     = *(const float4*)(a0 + i0);
      vp0[2 * p + 1] = *(const float4*)(a0 + D_ + i0);
    }
  }

  // prefix log2(beta) scan (overlaps load latency)
  if (tid < 64) {
    float x = log2f(fmaxf(bx0, 1e-30f));
#pragma unroll
    for (int off = 1; off < 64; off <<= 1) {
      float y = __shfl_up(x, off);
      if (tid >= off) x += y;
    }
    ls[tid] = x;
    const float tot0 = __shfl(x, 63);
    float z = log2f(fmaxf(bx1, 1e-30f));
#pragma unroll
    for (int off = 1; off < 64; off <<= 1) {
      float y = __shfl_up(z, off);
      if (tid >= off) z += y;
    }
    ls[64 + tid] = z + tot0;
  }

  // ---- stage QB row-major bf16 from registers ----
#pragma unroll
  for (int p = 0; p < 8; ++p)
    *(s8v*)&QB[qt * 264 + qc + p * 32] = pack8(qp[2 * p], qp[2 * p + 1]);
  __syncthreads();
  if (tid < L_) cv[tid] = exp2f(ls[tid]);   // c_t

  const int lane = tid & 63, wave = tid >> 6;
  const int quad = lane >> 4, l15 = lane & 15;
  const int j0w = wave * 32;

  // ---- phase A: T = Q K^T.  wave w owns s-tile w; loops all 8 t-tiles ----
  {
    const int mA = wave * 16;           // s-tile base
    f4v accA[8];
#pragma unroll
    for (int i = 0; i < 8; ++i) accA[i] = (f4v){0.f, 0.f, 0.f, 0.f};
#pragma unroll
    for (int kd = 0; kd < 8; ++kd) {
      const int d0 = kd * 32 + quad * 8;
      const float* krow = kbase + (size_t)(mA + l15) * D_ + d0;
      const s8v afr = pack8(*(const float4*)krow, *(const float4*)(krow + 4));
#pragma unroll
      for (int nt = 0; nt < 8; ++nt) {
        const s8v bf = *(const s8v*)&QB[(nt * 16 + l15) * 264 + d0];
        accA[nt] = __builtin_amdgcn_mfma_f32_16x16x32_bf16(afr, bf, accA[nt],
                                                           0, 0, 0);
      }
    }
    // rows = s (quad*4+r), cols = t (l15): mask+decay, pack s-pairs
#pragma unroll
    for (int nt = 0; nt < 8; ++nt) {
      const int t = nt * 16 + l15;
      const float lt = ls[t];
      const int s0 = mA + quad * 4;
      float v4[4];
#pragma unroll
      for (int r = 0; r < 4; ++r) {
        const int s = s0 + r;
        v4[r] = (s <= t) ? accA[nt][r] * exp2f(lt - ls[s]) : 0.f;
      }
      uint2 w;
      w.x = pk2(v4[0], v4[1]);
      w.y = pk2(v4[2], v4[3]);
      *(uint2*)&Tm[t * 136 + s0] = w;
    }
  }

  // ---- stage VT half 0 from prefetched registers (no global wait) ----
  {
#pragma unroll
    for (int p = 0; p < 4; ++p) {
      const int i0 = p * 64 + iL3 * 4;
      const float4 a0 = vp0[2 * p], a1 = vp0[2 * p + 1];
      *(u32*)&VT[(i0 + 0) * STK + s03] = pk2(a0.x, a1.x);
      *(u32*)&VT[(i0 + 1) * STK + s03] = pk2(a0.y, a1.y);
      *(u32*)&VT[(i0 + 2) * STK + s03] = pk2(a0.z, a1.z);
      *(u32*)&VT[(i0 + 3) * STK + s03] = pk2(a0.w, a1.w);
    }
  }

  // preload first H k-step (global, independent of LDS)
  s8v hc[2];
#pragma unroll
  for (int mt = 0; mt < 2; ++mt)
    hc[mt] = *(const s8v*)(Hb + (size_t)(j0w + mt * 16 + l15) * D_ + quad * 8);

  __syncthreads();   // Tm + VT(h0) visible

  // issue V half-1 loads AFTER the barrier: they drain under the QH loop
  float4 vp1[8];
  {
    const float* b0 = vbase + (size_t)(64 + s03) * D_;
#pragma unroll
    for (int p = 0; p < 4; ++p) {
      const int i0 = p * 64 + iL3 * 4;
      vp1[2 * p]     = *(const float4*)(b0 + i0);
      vp1[2 * p + 1] = *(const float4*)(b0 + D_ + i0);
    }
  }

  // ---- Q @ H into acc, H loads pipelined one step ahead ----
  f4v acc[2][8];
#pragma unroll
  for (int mt = 0; mt < 2; ++mt)
#pragma unroll
    for (int nt = 0; nt < 8; ++nt) acc[mt][nt] = (f4v){0.f, 0.f, 0.f, 0.f};

#pragma unroll
  for (int ks = 0; ks < 8; ++ks) {
    const int io = ks * 32 + quad * 8;
    s8v hn[2] = {hc[0], hc[1]};
    if (ks < 7) {
#pragma unroll
      for (int mt = 0; mt < 2; ++mt)
        hn[mt] = *(const s8v*)(Hb + (size_t)(j0w + mt * 16 + l15) * D_ +
                               io + 32);
    }
    s8v bfq[8];
#pragma unroll
    for (int nt = 0; nt < 8; ++nt)
      bfq[nt] = *(const s8v*)&QB[(nt * 16 + l15) * 264 + io];
#pragma unroll
    for (int mt = 0; mt < 2; ++mt)
#pragma unroll
      for (int nt = 0; nt < 8; ++nt)
        acc[mt][nt] = __builtin_amdgcn_mfma_f32_16x16x32_bf16(
            hc[mt], bfq[nt], acc[mt][nt], 0, 0, 0);
    hc[0] = hn[0]; hc[1] = hn[1];
  }
  // scale by c_t  (t = nt*16 + l15 constant per lane per nt)
#pragma unroll
  for (int nt = 0; nt < 8; ++nt) {
    const float ct = cv[nt * 16 + l15];
#pragma unroll
    for (int mt = 0; mt < 2; ++mt) {
      acc[mt][nt][0] *= ct; acc[mt][nt][1] *= ct;
      acc[mt][nt][2] *= ct; acc[mt][nt][3] *= ct;
    }
  }

  // ---- Tm @ V half 0 (VT already staged) ----
#pragma unroll
  for (int ks = 0; ks < 2; ++ks) {
    const int so = ks * 32 + quad * 8;
    s8v afv[2], bfv[8];
#pragma unroll
    for (int mt = 0; mt < 2; ++mt)
      afv[mt] = *(const s8v*)&VT[(j0w + mt * 16 + l15) * STK + so];
#pragma unroll
    for (int nt = 0; nt < 8; ++nt)
      bfv[nt] = *(const s8v*)&Tm[(nt * 16 + l15) * 136 + so];
#pragma unroll
    for (int mt = 0; mt < 2; ++mt)
#pragma unroll
      for (int nt = 0; nt < 8; ++nt)
        acc[mt][nt] = __builtin_amdgcn_mfma_f32_16x16x32_bf16(
            afv[mt], bfv[nt], acc[mt][nt], 0, 0, 0);
  }

  // ---- Tm @ V half 1: restage VT from registers (loads landed long ago) ----
  __syncthreads();   // all h0 reads done before overwrite; vp1 drained here
  {
#pragma unroll
    for (int p = 0; p < 4; ++p) {
      const int i0 = p * 64 + iL3 * 4;
      const float4 a0 = vp1[2 * p], a1 = vp1[2 * p + 1];
      *(u32*)&VT[(i0 + 0) * STK + s03] = pk2(a0.x, a1.x);
      *(u32*)&VT[(i0 + 1) * STK + s03] = pk2(a0.y, a1.y);
      *(u32*)&VT[(i0 + 2) * STK + s03] = pk2(a0.z, a1.z);
      *(u32*)&VT[(i0 + 3) * STK + s03] = pk2(a0.w, a1.w);
    }
  }
  __syncthreads();
#pragma unroll
  for (int ks = 0; ks < 2; ++ks) {
    const int so = ks * 32 + quad * 8;
    s8v afv[2], bfv[8];
#pragma unroll
    for (int mt = 0; mt < 2; ++mt)
      afv[mt] = *(const s8v*)&VT[(j0w + mt * 16 + l15) * STK + so];
#pragma unroll
    for (int nt = 0; nt < 8; ++nt)
      bfv[nt] = *(const s8v*)&Tm[(nt * 16 + l15) * 136 + 64 + so];
#pragma unroll
    for (int mt = 0; mt < 2; ++mt)
#pragma unroll
      for (int nt = 0; nt < 8; ++nt)
        acc[mt][nt] = __builtin_amdgcn_mfma_f32_16x16x32_bf16(
            afv[mt], bfv[nt], acc[mt][nt], 0, 0, 0);
  }

  // epilogue: float4 stores (r runs along j)
  float* ob = outg + ((size_t)b * S_ + (size_t)c * L_) * D_;
#pragma unroll
  for (int mt = 0; mt < 2; ++mt)
#pragma unroll
    for (int nt = 0; nt < 8; ++nt) {
      const int t = nt * 16 + l15;
      const int j0 = j0w + mt * 16 + quad * 4;
      float4 o;
      o.x = acc[mt][nt][0]; o.y = acc[mt][nt][1];
      o.z = acc[mt][nt][2]; o.w = acc[mt][nt][3];
      *(float4*)(ob + (size_t)t * D_ + j0) = o;
    }
}

// ---------------------------------------------------------------------------
extern "C" void kernel_launch(void* const* d_in, const int* in_sizes, int n_in,
                              void* d_out, int out_size, void* d_ws,
                              size_t ws_size, hipStream_t stream) {
  const float* q = (const float*)d_in[0];
  const float* k = (const float*)d_in[1];
  const float* v = (const float*)d_in[2];
  const float* beta = (const float*)d_in[3];
  float* out = (float*)d_out;

  u16* A = (u16*)d_ws;                                   // 33.5 MB bf16 state
  float* P = (float*)((char*)d_ws + (size_t)BC_ * D_ * D_ * sizeof(u16));

  ks_summary14<<<dim3(BC_), dim3(512), 0, stream>>>(k, v, beta, A, P);
  ks_scan14<<<dim3(512), dim3(256), 0, stream>>>(A, P);
  ks_output14<<<dim3(BC_), dim3(512), 0, stream>>>(q, k, v, beta, A, out);
}